// Round 6
// baseline (553.625 us; speedup 1.0000x reference)
//
#include <hip/hip_runtime.h>
#include <hip/hip_bf16.h>

#define NB 64
#define NT 25
#define NS 50
#define EMBD 300
#define NFILT 100
#define HD 256
#define NOUT 31
#define NBT (NB*NT)

#define KP3 928
#define KP4 1216
#define KP5 1504
#define XS_LEN 15104   // 50*300 = 15000 + pad (max read 45*300+1504 = 15004)

typedef __attribute__((ext_vector_type(8))) short short8;
typedef __attribute__((ext_vector_type(4))) float f32x4;

__device__ __forceinline__ float hsum4(float4 a) { return (a.x + a.y) + (a.z + a.w); }
__device__ __forceinline__ void fma4(float4& a, float4 w, float4 x) {
    a.x = fmaf(w.x, x.x, a.x); a.y = fmaf(w.y, x.y, a.y);
    a.z = fmaf(w.z, x.z, a.z); a.w = fmaf(w.w, x.w, a.w);
}
__device__ __forceinline__ float sigmoidf_(float x) { return 1.0f / (1.0f + __expf(-x)); }
__device__ __forceinline__ float tanh_fast(float x) {
    x = fminf(fmaxf(x, -15.0f), 15.0f);
    const float e = __expf(2.0f * x);
    return (e - 1.0f) / (e + 1.0f);
}

__device__ __forceinline__ unsigned short f2bf(float f) {
    union { float f; unsigned u; } v; v.f = f;
    unsigned r = v.u + 0x7FFF + ((v.u >> 16) & 1);   // RNE
    return (unsigned short)(r >> 16);
}

// 8 bf16 from an 8-byte-aligned LDS address
__device__ __forceinline__ short8 ld8_a8(const unsigned short* p) {
    short8 r;
    ((uint2*)&r)[0] = *(const uint2*)p;
    ((uint2*)&r)[1] = *(const uint2*)(p + 4);
    return r;
}

// ---------------- conv weight prep: f32 -> bf16, K padded to 32-mult, F padded to 112
__global__ __launch_bounds__(256) void k_prep(
    const float* __restrict__ w3, const float* __restrict__ w4, const float* __restrict__ w5,
    unsigned short* __restrict__ wb)
{
    const int S0 = 112 * KP3, S1 = S0 + 112 * KP4, S2 = S1 + 112 * KP5;
    int idx = blockIdx.x * 256 + threadIdx.x;
    if (idx >= S2) return;
    int rel, Kp, K; const float* src;
    if (idx < S0)      { rel = idx;      Kp = KP3; K = 900;  src = w3; }
    else if (idx < S1) { rel = idx - S0; Kp = KP4; K = 1200; src = w4; }
    else               { rel = idx - S1; Kp = KP5; K = 1500; src = w5; }
    int f = rel / Kp, k = rel - f * Kp;
    float v = (f < NFILT && k < K) ? src[(size_t)f * K + k] : 0.0f;
    wb[idx] = f2bf(v);
}

// ---------------- LSTM weight prep: whh/whh_r f32 -> bf16, rows reordered n = j*4+gate
__global__ __launch_bounds__(256) void k_prep2(
    const float* __restrict__ whh, const float* __restrict__ whh_r,
    unsigned short* __restrict__ wb2)
{
    const int idx = blockIdx.x * 256 + threadIdx.x;      // grid = 2048*256 = 524288 exact
    const int dir = idx >> 18;
    const int rem = idx & 262143;
    const int n = rem >> 8, k = rem & 255;
    const int j = n >> 2, gate = n & 3;
    const float* src = dir ? whh_r : whh;
    wb2[idx] = f2bf(src[(size_t)(gate * 256 + j) * 256 + k]);
}

// ---------------- conv inner MAC loop: compile-time NKS, depth-4 W ring ----
template<int NKS>
__device__ __forceinline__ void conv_mac(
    const unsigned short* __restrict__ wrow,
    const unsigned short* __restrict__ xb0, const unsigned short* __restrict__ xb1,
    f32x4& a00, f32x4& a01, f32x4& a02, f32x4& a10, f32x4& a11, f32x4& a12)
{
    short8 wr0 = *(const short8*)(wrow);
    short8 wr1 = *(const short8*)(wrow + 32);
    short8 wr2 = *(const short8*)(wrow + 64);
    short8 wr3 = *(const short8*)(wrow + 96);
    #pragma unroll
    for (int ks = 0; ks < NKS; ++ks) {
        const int k0 = ks * 32;
        short8 bfrag;
        if ((ks & 3) == 0) bfrag = wr0;
        else if ((ks & 3) == 1) bfrag = wr1;
        else if ((ks & 3) == 2) bfrag = wr2;
        else bfrag = wr3;
        short8 p0 = ld8_a8(xb0 + k0);
        short8 p1 = ld8_a8(xb0 + 16 * 300 + k0);
        short8 p2 = ld8_a8(xb0 + 32 * 300 + k0);
        short8 q0 = ld8_a8(xb1 + k0);
        short8 q1 = ld8_a8(xb1 + 16 * 300 + k0);
        short8 q2 = ld8_a8(xb1 + 32 * 300 + k0);
        a00 = __builtin_amdgcn_mfma_f32_16x16x32_bf16(p0, bfrag, a00, 0, 0, 0);
        a01 = __builtin_amdgcn_mfma_f32_16x16x32_bf16(p1, bfrag, a01, 0, 0, 0);
        a02 = __builtin_amdgcn_mfma_f32_16x16x32_bf16(p2, bfrag, a02, 0, 0, 0);
        a10 = __builtin_amdgcn_mfma_f32_16x16x32_bf16(q0, bfrag, a10, 0, 0, 0);
        a11 = __builtin_amdgcn_mfma_f32_16x16x32_bf16(q1, bfrag, a11, 0, 0, 0);
        a12 = __builtin_amdgcn_mfma_f32_16x16x32_bf16(q2, bfrag, a12, 0, 0, 0);
        // refill the slot just consumed with ks+4 (issued after its readers)
        if (ks + 4 < NKS) {
            short8 nv = *(const short8*)(wrow + (ks + 4) * 32);
            if ((ks & 3) == 0) wr0 = nv;
            else if ((ks & 3) == 1) wr1 = nv;
            else if ((ks & 3) == 2) wr2 = nv;
            else wr3 = nv;
        }
    }
}

// ---------------- conv: 2 samples per WG, 512 threads; MFMA + depth-4 W ring ----
__global__ __launch_bounds__(512, 1) void k_conv(
    const int* __restrict__ tok, const float* __restrict__ emb,
    const unsigned short* __restrict__ wb,
    const float* __restrict__ b3, const float* __restrict__ b4, const float* __restrict__ b5,
    float* __restrict__ rin)
{
    __shared__ unsigned short xs[2][XS_LEN];   // ~118 KB
    const int bt0 = blockIdx.x * 2;
    const int tid = threadIdx.x;
    for (int i4 = tid; i4 < 2 * NS * 75; i4 += 512) {
        const int smp = i4 / (NS * 75);
        const int rem = i4 - smp * (NS * 75);
        const int s = rem / 75, e4 = rem - s * 75;
        const int t = tok[(bt0 + smp) * NS + s];
        float4 v = ((const float4*)(emb + (size_t)t * EMBD))[e4];
        uint2 pk;
        pk.x = (unsigned)f2bf(v.x) | ((unsigned)f2bf(v.y) << 16);
        pk.y = (unsigned)f2bf(v.z) | ((unsigned)f2bf(v.w) << 16);
        *(uint2*)(&xs[smp][s * 300 + e4 * 4]) = pk;
    }
    for (int i = NS * EMBD + tid; i < XS_LEN; i += 512) { xs[0][i] = 0; xs[1][i] = 0; }
    __syncthreads();

    const int wave = tid >> 6, lane = tid & 63;
    const int col = lane & 15, kg = lane >> 4;

    for (int job = wave; job < 21; job += 8) {
        const int fsi = job / 7, ntile = job - fsi * 7;
        int Kp, P, obase; const unsigned short* W; const float* bias;
        if (fsi == 0)      { Kp = KP3; P = 48; W = wb;                       bias = b3; obase = 0; }
        else if (fsi == 1) { Kp = KP4; P = 47; W = wb + 112 * KP3;           bias = b4; obase = NFILT; }
        else               { Kp = KP5; P = 46; W = wb + 112 * (KP3 + KP4);   bias = b5; obase = 2 * NFILT; }

        const unsigned short* wrow = W + (size_t)(ntile * 16 + col) * Kp + kg * 8;
        const unsigned short* xb0 = &xs[0][col * 300 + kg * 8];
        const unsigned short* xb1 = &xs[1][col * 300 + kg * 8];
        f32x4 a00 = {0,0,0,0}, a01 = {0,0,0,0}, a02 = {0,0,0,0};
        f32x4 a10 = {0,0,0,0}, a11 = {0,0,0,0}, a12 = {0,0,0,0};

        if (fsi == 0)      conv_mac<KP3/32>(wrow, xb0, xb1, a00, a01, a02, a10, a11, a12);
        else if (fsi == 1) conv_mac<KP4/32>(wrow, xb0, xb1, a00, a01, a02, a10, a11, a12);
        else               conv_mac<KP5/32>(wrow, xb0, xb1, a00, a01, a02, a10, a11, a12);

        float pm0 = -1e30f, pm1 = -1e30f;
        #pragma unroll
        for (int reg = 0; reg < 4; ++reg) {
            pm0 = fmaxf(pm0, a00[reg]); pm0 = fmaxf(pm0, a01[reg]);
            pm1 = fmaxf(pm1, a10[reg]); pm1 = fmaxf(pm1, a11[reg]);
            const int r2 = 32 + kg * 4 + reg;
            if (r2 < P) { pm0 = fmaxf(pm0, a02[reg]); pm1 = fmaxf(pm1, a12[reg]); }
        }
        pm0 = fmaxf(pm0, __shfl_xor(pm0, 16, 64));
        pm0 = fmaxf(pm0, __shfl_xor(pm0, 32, 64));
        pm1 = fmaxf(pm1, __shfl_xor(pm1, 16, 64));
        pm1 = fmaxf(pm1, __shfl_xor(pm1, 32, 64));
        if (lane < 16) {
            const int f = ntile * 16 + lane;
            if (f < NFILT) {
                const float bb = bias[f];
                rin[(size_t)bt0 * (3 * NFILT) + obase + f]       = fmaxf(0.0f, pm0 + bb);
                rin[(size_t)(bt0 + 1) * (3 * NFILT) + obase + f] = fmaxf(0.0f, pm1 + bb);
            }
        }
    }
}

// ---------------- input-gate GEMM; writes gin[dir][t][b][n'], n' = j*4+gate ----
__global__ __launch_bounds__(256) void k_gin(
    const float* __restrict__ rin,
    const float* __restrict__ wih,   const float* __restrict__ bih,   const float* __restrict__ bhh,
    const float* __restrict__ wih_r, const float* __restrict__ bih_r, const float* __restrict__ bhh_r,
    float* __restrict__ gin)
{
    __shared__ float xsh[8 * EMBD];
    const int bt0 = blockIdx.x * 8;
    const int tid = threadIdx.x;
    const float4* src = (const float4*)(rin + (size_t)bt0 * EMBD);
    for (int i4 = tid; i4 < 8 * EMBD / 4; i4 += 256) ((float4*)xsh)[i4] = src[i4];
    __syncthreads();
    for (int g2 = tid; g2 < 2 * 1024; g2 += 256) {
        const int d = g2 >> 10;
        const int g = g2 & 1023;
        const float* wp = (d ? wih_r : wih) + (size_t)g * EMBD;
        const float bb = d ? (bih_r[g] + bhh_r[g]) : (bih[g] + bhh[g]);
        const float4* w4p = (const float4*)wp;
        float4 acc[8];
        #pragma unroll
        for (int r = 0; r < 8; ++r) acc[r] = {0,0,0,0};
        for (int k = 0; k < EMBD / 4; ++k) {
            const float4 wv = w4p[k];
            #pragma unroll
            for (int r = 0; r < 8; ++r) fma4(acc[r], wv, ((const float4*)(xsh + r * EMBD))[k]);
        }
        const int gp = ((g & 255) << 2) | (g >> 8);   // j*4 + gate
        #pragma unroll
        for (int r = 0; r < 8; ++r) {
            const int bt = bt0 + r;
            const int b = bt / NT, t = bt - b * NT;
            gin[(((size_t)d * NT + t) * NB + b) * 1024 + gp] = hsum4(acc[r]) + bb;
        }
    }
}

// ---------------- recurrence: 8 WGs (2 dir x 4 batch-quarters); deep W prefetch ----
__global__ __launch_bounds__(512, 1) void k_lstm(
    const float* __restrict__ gin,          // [dir][t][64][1024] f32, n' = j*4+gate
    const unsigned short* __restrict__ wb2, // [dir][1024][256] bf16
    float* __restrict__ hs)                 // [dir][b*NT+t][256] f32
{
    const int bid = blockIdx.x;
    const int dir = bid >> 2, bq = bid & 3;
    const int tid = threadIdx.x;
    const int wave = tid >> 6, lane = tid & 63;
    const int l15 = lane & 15, kg = lane >> 4;

    __shared__ unsigned short hb[2][16 * 264];   // 2 x 8448 B
    __shared__ float slab[8][32 * 20];           // per-wave transpose scratch

    for (int i = tid; i < 16 * 264; i += 512) hb[0][i] = 0;
    __syncthreads();

    const unsigned short* wb_w = wb2 + (size_t)dir * (1024 * 256)
                               + (size_t)(wave * 128 + l15) * 256 + kg * 8;
    const float* gb = gin + (size_t)dir * (NT * NB * 1024);
    float* hsb = hs + (size_t)dir * NBT * HD;

    float c[8];
    #pragma unroll
    for (int q = 0; q < 8; ++q) c[q] = 0.0f;

    const int j_local = lane & 7;
    const int b_lo = (lane >> 3) & 7;

    for (int s = 0; s < NT; ++s) {
        const int t = dir ? s : (NT - 1 - s);
        const unsigned short* hc = hb[s & 1];
        unsigned short* hn = hb[(s + 1) & 1];

        // prefetch this step's gin (independent of the GEMM -> latency hidden)
        float4 gxr[8];
        #pragma unroll
        for (int ntp = 0; ntp < 4; ++ntp)
            #pragma unroll
            for (int p = 0; p < 2; ++p) {
                const int b_row = b_lo + p * 8;
                const int bglob = bq * 16 + b_row;
                const int j_g = wave * 32 + ntp * 8 + j_local;
                gxr[ntp * 2 + p] = *(const float4*)(gb + (((size_t)t * NB + bglob) << 10) + j_g * 4);
            }

        // stage all 8 A-fragments (h rows) from LDS up front
        short8 avb[8];
        #pragma unroll
        for (int kk = 0; kk < 8; ++kk)
            avb[kk] = *(const short8*)(hc + l15 * 264 + kk * 32 + kg * 8);

        f32x4 acc[8];
        #pragma unroll
        for (int nt = 0; nt < 8; ++nt) acc[nt] = (f32x4){0.f, 0.f, 0.f, 0.f};

        // 3-slot W ring: 24 loads in flight, slot refilled after its MFMAs consume it
        short8 wbuf[3][8];
        #pragma unroll
        for (int d = 0; d < 3; ++d)
            #pragma unroll
            for (int nt = 0; nt < 8; ++nt)
                wbuf[d][nt] = *(const short8*)(wb_w + nt * 4096 + d * 32);
        #pragma unroll
        for (int kk = 0; kk < 8; ++kk) {
            const int cur = kk % 3;
            #pragma unroll
            for (int nt = 0; nt < 8; ++nt)
                acc[nt] = __builtin_amdgcn_mfma_f32_16x16x32_bf16(avb[kk], wbuf[cur][nt], acc[nt], 0, 0, 0);
            if (kk + 3 < 8) {
                #pragma unroll
                for (int nt = 0; nt < 8; ++nt)
                    wbuf[cur][nt] = *(const short8*)(wb_w + nt * 4096 + (kk + 3) * 32);
            }
        }

        // per-wave slab transpose -> activations -> c,h update
        float* sw = &slab[wave][0];
        #pragma unroll
        for (int ntp = 0; ntp < 4; ++ntp) {
            *(f32x4*)(sw + l15 * 20 + kg * 4)        = acc[2 * ntp];
            *(f32x4*)(sw + (16 + l15) * 20 + kg * 4) = acc[2 * ntp + 1];
            #pragma unroll
            for (int p = 0; p < 2; ++p) {
                const int b_row = b_lo + p * 8;
                const int bglob = bq * 16 + b_row;
                const int j_g = wave * 32 + ntp * 8 + j_local;
                const float gI = sw[(j_local * 4 + 0) * 20 + b_row];
                const float gF = sw[(j_local * 4 + 1) * 20 + b_row];
                const float gG = sw[(j_local * 4 + 2) * 20 + b_row];
                const float gO = sw[(j_local * 4 + 3) * 20 + b_row];
                const float4 gx = gxr[ntp * 2 + p];
                const float vi = sigmoidf_(gI + gx.x);
                const float vf = sigmoidf_(gF + gx.y);
                const float vg = tanh_fast(gG + gx.z);
                const float vo = sigmoidf_(gO + gx.w);
                const int ci = ntp * 2 + p;
                const float cc = vf * c[ci] + vi * vg;
                c[ci] = cc;
                const float hh = vo * tanh_fast(cc);
                hn[b_row * 264 + j_g] = f2bf(hh);
                hsb[((size_t)bglob * NT + t) * HD + j_g] = hh;
            }
        }
        __syncthreads();
    }
}

// ---------------- output projection + sigmoid ----
__global__ __launch_bounds__(64) void k_out(
    const float* __restrict__ hs, const float* __restrict__ w, const float* __restrict__ bias,
    float* __restrict__ out)
{
    __shared__ float hsh[2 * HD];
    const int bt = blockIdx.x;
    const int tid = threadIdx.x;
    const float4* rev4 = (const float4*)(hs + (size_t)bt * HD);
    const float4* fwd4 = (const float4*)(hs + ((size_t)NBT + bt) * HD);
    for (int i = tid; i < 2 * HD / 4; i += 64)
        ((float4*)hsh)[i] = (i < HD / 4) ? rev4[i] : fwd4[i - HD / 4];
    __syncthreads();
    if (tid < NOUT) {
        const float4* wr = (const float4*)(w + (size_t)tid * (2 * HD));
        float4 acc{0,0,0,0};
        for (int k = 0; k < 2 * HD / 4; ++k) fma4(acc, wr[k], ((const float4*)hsh)[k]);
        out[(size_t)bt * NOUT + tid] = sigmoidf_(hsum4(acc) + bias[tid]);
    }
}

extern "C" void kernel_launch(void* const* d_in, const int* in_sizes, int n_in,
                              void* d_out, int out_size, void* d_ws, size_t ws_size,
                              hipStream_t stream)
{
    const int*   tok   = (const int*)d_in[0];
    const float* emb   = (const float*)d_in[1];
    const float* w3    = (const float*)d_in[2];
    const float* b3    = (const float*)d_in[3];
    const float* w4    = (const float*)d_in[4];
    const float* b4    = (const float*)d_in[5];
    const float* w5    = (const float*)d_in[6];
    const float* b5    = (const float*)d_in[7];
    const float* wih   = (const float*)d_in[8];
    const float* whh   = (const float*)d_in[9];
    const float* bih   = (const float*)d_in[10];
    const float* bhh   = (const float*)d_in[11];
    const float* wih_r = (const float*)d_in[12];
    const float* whh_r = (const float*)d_in[13];
    const float* bih_r = (const float*)d_in[14];
    const float* bhh_r = (const float*)d_in[15];
    const float* h2o_w = (const float*)d_in[16];
    const float* h2o_b = (const float*)d_in[17];

    float* ws  = (float*)d_ws;
    float* rin = ws;                                  // 480,000 f (dead after k_gin)
    float* gin = rin + (size_t)NBT * 3 * NFILT;       // 3,276,800 f  [dir][t][b][1024]
    float* hs  = gin + (size_t)2 * NBT * 1024;        // 819,200 f
    unsigned short* wb  = (unsigned short*)gin;       // conv bf16 W overlays gin
    unsigned short* wb2 = (unsigned short*)rin;       // LSTM bf16 W overlays rin

    k_prep <<<1596, 256, 0, stream>>>(w3, w4, w5, wb);
    k_conv <<<NBT / 2, 512, 0, stream>>>(tok, emb, wb, b3, b4, b5, rin);
    k_gin  <<<NBT / 8, 256, 0, stream>>>(rin, wih, bih, bhh, wih_r, bih_r, bhh_r, gin);
    k_prep2<<<2048, 256, 0, stream>>>(whh, whh_r, wb2);
    k_lstm <<<8, 512, 0, stream>>>(gin, wb2, hs);
    k_out  <<<NBT, 64, 0, stream>>>(hs, h2o_w, h2o_b, (float*)d_out);
}

// Round 7
// 514.015 us; speedup vs baseline: 1.0771x; 1.0771x over previous
//
#include <hip/hip_runtime.h>
#include <hip/hip_bf16.h>

#define NB 64
#define NT 25
#define NS 50
#define EMBD 300
#define NFILT 100
#define HD 256
#define NOUT 31
#define NBT (NB*NT)

#define KP3 928
#define KP4 1216
#define KP5 1504
#define XS_LEN 15104   // 50*300 = 15000 + pad (max read 45*300+1504 = 15004)

typedef __attribute__((ext_vector_type(8))) short short8;
typedef __attribute__((ext_vector_type(4))) float f32x4;

__device__ __forceinline__ float hsum4(float4 a) { return (a.x + a.y) + (a.z + a.w); }
__device__ __forceinline__ void fma4(float4& a, float4 w, float4 x) {
    a.x = fmaf(w.x, x.x, a.x); a.y = fmaf(w.y, x.y, a.y);
    a.z = fmaf(w.z, x.z, a.z); a.w = fmaf(w.w, x.w, a.w);
}
__device__ __forceinline__ float sigmoidf_(float x) { return 1.0f / (1.0f + __expf(-x)); }
__device__ __forceinline__ float tanh_fast(float x) {
    x = fminf(fmaxf(x, -15.0f), 15.0f);
    const float e = __expf(2.0f * x);
    return (e - 1.0f) / (e + 1.0f);
}

__device__ __forceinline__ unsigned short f2bf(float f) {
    union { float f; unsigned u; } v; v.f = f;
    unsigned r = v.u + 0x7FFF + ((v.u >> 16) & 1);   // RNE
    return (unsigned short)(r >> 16);
}

// 8 bf16 from an 8-byte-aligned LDS address
__device__ __forceinline__ short8 ld8_a8(const unsigned short* p) {
    short8 r;
    ((uint2*)&r)[0] = *(const uint2*)p;
    ((uint2*)&r)[1] = *(const uint2*)(p + 4);
    return r;
}

// ---------------- conv weight prep: f32 -> bf16, K padded to 32-mult, F padded to 112
__global__ __launch_bounds__(256) void k_prep(
    const float* __restrict__ w3, const float* __restrict__ w4, const float* __restrict__ w5,
    unsigned short* __restrict__ wb)
{
    const int S0 = 112 * KP3, S1 = S0 + 112 * KP4, S2 = S1 + 112 * KP5;
    int idx = blockIdx.x * 256 + threadIdx.x;
    if (idx >= S2) return;
    int rel, Kp, K; const float* src;
    if (idx < S0)      { rel = idx;      Kp = KP3; K = 900;  src = w3; }
    else if (idx < S1) { rel = idx - S0; Kp = KP4; K = 1200; src = w4; }
    else               { rel = idx - S1; Kp = KP5; K = 1500; src = w5; }
    int f = rel / Kp, k = rel - f * Kp;
    float v = (f < NFILT && k < K) ? src[(size_t)f * K + k] : 0.0f;
    wb[idx] = f2bf(v);
}

// ---------------- LSTM weight prep: whh/whh_r f32 -> bf16, rows reordered n = j*4+gate
__global__ __launch_bounds__(256) void k_prep2(
    const float* __restrict__ whh, const float* __restrict__ whh_r,
    unsigned short* __restrict__ wb2)
{
    const int idx = blockIdx.x * 256 + threadIdx.x;      // grid = 2048*256 = 524288 exact
    const int dir = idx >> 18;
    const int rem = idx & 262143;
    const int n = rem >> 8, k = rem & 255;
    const int j = n >> 2, gate = n & 3;
    const float* src = dir ? whh_r : whh;
    wb2[idx] = f2bf(src[(size_t)(gate * 256 + j) * 256 + k]);
}

// ---------------- conv: 2 samples per WG, 512 threads; MFMA + depth-2 W prefetch ----
// (reverted to the R5 form: depth-2 ring, plain launch_bounds(512))
__global__ __launch_bounds__(512) void k_conv(
    const int* __restrict__ tok, const float* __restrict__ emb,
    const unsigned short* __restrict__ wb,
    const float* __restrict__ b3, const float* __restrict__ b4, const float* __restrict__ b5,
    float* __restrict__ rin)
{
    __shared__ unsigned short xs[2][XS_LEN];   // ~118 KB
    const int bt0 = blockIdx.x * 2;
    const int tid = threadIdx.x;
    for (int i4 = tid; i4 < 2 * NS * 75; i4 += 512) {
        const int smp = i4 / (NS * 75);
        const int rem = i4 - smp * (NS * 75);
        const int s = rem / 75, e4 = rem - s * 75;
        const int t = tok[(bt0 + smp) * NS + s];
        float4 v = ((const float4*)(emb + (size_t)t * EMBD))[e4];
        uint2 pk;
        pk.x = (unsigned)f2bf(v.x) | ((unsigned)f2bf(v.y) << 16);
        pk.y = (unsigned)f2bf(v.z) | ((unsigned)f2bf(v.w) << 16);
        *(uint2*)(&xs[smp][s * 300 + e4 * 4]) = pk;
    }
    for (int i = NS * EMBD + tid; i < XS_LEN; i += 512) { xs[0][i] = 0; xs[1][i] = 0; }
    __syncthreads();

    const int wave = tid >> 6, lane = tid & 63;
    const int col = lane & 15, kg = lane >> 4;

    for (int job = wave; job < 21; job += 8) {
        const int fsi = job / 7, ntile = job - fsi * 7;
        int Kp, P, obase; const unsigned short* W; const float* bias;
        if (fsi == 0)      { Kp = KP3; P = 48; W = wb;                       bias = b3; obase = 0; }
        else if (fsi == 1) { Kp = KP4; P = 47; W = wb + 112 * KP3;           bias = b4; obase = NFILT; }
        else               { Kp = KP5; P = 46; W = wb + 112 * (KP3 + KP4);   bias = b5; obase = 2 * NFILT; }

        const unsigned short* wrow = W + (size_t)(ntile * 16 + col) * Kp + kg * 8;
        const unsigned short* xb0 = &xs[0][col * 300 + kg * 8];
        const unsigned short* xb1 = &xs[1][col * 300 + kg * 8];
        f32x4 a00 = {0,0,0,0}, a01 = {0,0,0,0}, a02 = {0,0,0,0};
        f32x4 a10 = {0,0,0,0}, a11 = {0,0,0,0}, a12 = {0,0,0,0};

        const int nks = Kp / 32;
        short8 wr0 = *(const short8*)(wrow);
        short8 wr1 = *(const short8*)(wrow + 32);
        for (int ks = 0; ks < nks; ++ks) {
            const int k0 = ks * 32;
            short8 bfrag = wr0;
            wr0 = wr1;
            if (ks + 2 < nks) wr1 = *(const short8*)(wrow + k0 + 64);
            short8 p0 = ld8_a8(xb0 + k0);
            short8 p1 = ld8_a8(xb0 + 16 * 300 + k0);
            short8 p2 = ld8_a8(xb0 + 32 * 300 + k0);
            short8 q0 = ld8_a8(xb1 + k0);
            short8 q1 = ld8_a8(xb1 + 16 * 300 + k0);
            short8 q2 = ld8_a8(xb1 + 32 * 300 + k0);
            a00 = __builtin_amdgcn_mfma_f32_16x16x32_bf16(p0, bfrag, a00, 0, 0, 0);
            a01 = __builtin_amdgcn_mfma_f32_16x16x32_bf16(p1, bfrag, a01, 0, 0, 0);
            a02 = __builtin_amdgcn_mfma_f32_16x16x32_bf16(p2, bfrag, a02, 0, 0, 0);
            a10 = __builtin_amdgcn_mfma_f32_16x16x32_bf16(q0, bfrag, a10, 0, 0, 0);
            a11 = __builtin_amdgcn_mfma_f32_16x16x32_bf16(q1, bfrag, a11, 0, 0, 0);
            a12 = __builtin_amdgcn_mfma_f32_16x16x32_bf16(q2, bfrag, a12, 0, 0, 0);
        }

        float pm0 = -1e30f, pm1 = -1e30f;
        #pragma unroll
        for (int reg = 0; reg < 4; ++reg) {
            pm0 = fmaxf(pm0, a00[reg]); pm0 = fmaxf(pm0, a01[reg]);
            pm1 = fmaxf(pm1, a10[reg]); pm1 = fmaxf(pm1, a11[reg]);
            const int r2 = 32 + kg * 4 + reg;
            if (r2 < P) { pm0 = fmaxf(pm0, a02[reg]); pm1 = fmaxf(pm1, a12[reg]); }
        }
        pm0 = fmaxf(pm0, __shfl_xor(pm0, 16, 64));
        pm0 = fmaxf(pm0, __shfl_xor(pm0, 32, 64));
        pm1 = fmaxf(pm1, __shfl_xor(pm1, 16, 64));
        pm1 = fmaxf(pm1, __shfl_xor(pm1, 32, 64));
        if (lane < 16) {
            const int f = ntile * 16 + lane;
            if (f < NFILT) {
                const float bb = bias[f];
                rin[(size_t)bt0 * (3 * NFILT) + obase + f]       = fmaxf(0.0f, pm0 + bb);
                rin[(size_t)(bt0 + 1) * (3 * NFILT) + obase + f] = fmaxf(0.0f, pm1 + bb);
            }
        }
    }
}

// ---------------- input-gate GEMM; writes gin[dir][t][b][n'], n' = j*4+gate ----
__global__ __launch_bounds__(256) void k_gin(
    const float* __restrict__ rin,
    const float* __restrict__ wih,   const float* __restrict__ bih,   const float* __restrict__ bhh,
    const float* __restrict__ wih_r, const float* __restrict__ bih_r, const float* __restrict__ bhh_r,
    float* __restrict__ gin)
{
    __shared__ float xsh[8 * EMBD];
    const int bt0 = blockIdx.x * 8;
    const int tid = threadIdx.x;
    const float4* src = (const float4*)(rin + (size_t)bt0 * EMBD);
    for (int i4 = tid; i4 < 8 * EMBD / 4; i4 += 256) ((float4*)xsh)[i4] = src[i4];
    __syncthreads();
    for (int g2 = tid; g2 < 2 * 1024; g2 += 256) {
        const int d = g2 >> 10;
        const int g = g2 & 1023;
        const float* wp = (d ? wih_r : wih) + (size_t)g * EMBD;
        const float bb = d ? (bih_r[g] + bhh_r[g]) : (bih[g] + bhh[g]);
        const float4* w4p = (const float4*)wp;
        float4 acc[8];
        #pragma unroll
        for (int r = 0; r < 8; ++r) acc[r] = {0,0,0,0};
        for (int k = 0; k < EMBD / 4; ++k) {
            const float4 wv = w4p[k];
            #pragma unroll
            for (int r = 0; r < 8; ++r) fma4(acc[r], wv, ((const float4*)(xsh + r * EMBD))[k]);
        }
        const int gp = ((g & 255) << 2) | (g >> 8);   // j*4 + gate
        #pragma unroll
        for (int r = 0; r < 8; ++r) {
            const int bt = bt0 + r;
            const int b = bt / NT, t = bt - b * NT;
            gin[(((size_t)d * NT + t) * NB + b) * 1024 + gp] = hsum4(acc[r]) + bb;
        }
    }
}

// ---------------- recurrence: 8 WGs x 1024 threads (16 waves = 4/SIMD TLP) ----
// Wave w owns n-cols [w*64, w*64+64) (j = w*16..w*16+15). Depth-2 W ring fits 128 VGPR.
__global__ __launch_bounds__(1024, 1) void k_lstm(
    const float* __restrict__ gin,          // [dir][t][64][1024] f32, n' = j*4+gate
    const unsigned short* __restrict__ wb2, // [dir][1024][256] bf16
    float* __restrict__ hs)                 // [dir][b*NT+t][256] f32
{
    const int bid = blockIdx.x;
    const int dir = bid >> 2, bq = bid & 3;
    const int tid = threadIdx.x;
    const int wave = tid >> 6, lane = tid & 63;   // wave 0..15
    const int l15 = lane & 15, kg = lane >> 4;

    __shared__ unsigned short hb[2][16 * 264];   // 16.9 KB
    __shared__ float slab[16][32 * 20];          // 40 KB per-wave transpose scratch

    for (int i = tid; i < 16 * 264; i += 1024) hb[0][i] = 0;
    __syncthreads();

    const unsigned short* wb_w = wb2 + (size_t)dir * (1024 * 256)
                               + (size_t)(wave * 64 + l15) * 256 + kg * 8;
    const float* gb = gin + (size_t)dir * (NT * NB * 1024);
    float* hsb = hs + (size_t)dir * NBT * HD;

    float c[4] = {0.f, 0.f, 0.f, 0.f};

    const int j_local = lane & 7;   // j within 8-group
    const int b_lo = lane >> 3;     // 0..7

    for (int s = 0; s < NT; ++s) {
        const int t = dir ? s : (NT - 1 - s);
        const unsigned short* hc = hb[s & 1];
        unsigned short* hn = hb[(s + 1) & 1];

        // prefetch this step's gin quads (4 (b,j) pairs per thread)
        float4 gxr[4];
        #pragma unroll
        for (int t2 = 0; t2 < 2; ++t2)
            #pragma unroll
            for (int p = 0; p < 2; ++p) {
                const int b_row = b_lo + p * 8;
                const int bglob = bq * 16 + b_row;
                const int j_g = wave * 16 + t2 * 8 + j_local;
                gxr[t2 * 2 + p] = *(const float4*)(gb + (((size_t)t * NB + bglob) << 10) + j_g * 4);
            }

        // stage all 8 A-fragments (h rows) from LDS
        short8 avb[8];
        #pragma unroll
        for (int kk = 0; kk < 8; ++kk)
            avb[kk] = *(const short8*)(hc + l15 * 264 + kk * 32 + kg * 8);

        f32x4 acc[4];
        #pragma unroll
        for (int nt = 0; nt < 4; ++nt) acc[nt] = (f32x4){0.f, 0.f, 0.f, 0.f};

        // depth-2 W ring: 8 loads in flight per wave; 4 waves/SIMD cover the rest
        short8 wbuf[2][4];
        #pragma unroll
        for (int nt = 0; nt < 4; ++nt) {
            wbuf[0][nt] = *(const short8*)(wb_w + nt * 4096);
            wbuf[1][nt] = *(const short8*)(wb_w + nt * 4096 + 32);
        }
        #pragma unroll
        for (int kk = 0; kk < 8; ++kk) {
            const int cur = kk & 1;
            #pragma unroll
            for (int nt = 0; nt < 4; ++nt)
                acc[nt] = __builtin_amdgcn_mfma_f32_16x16x32_bf16(avb[kk], wbuf[cur][nt], acc[nt], 0, 0, 0);
            if (kk + 2 < 8) {
                #pragma unroll
                for (int nt = 0; nt < 4; ++nt)
                    wbuf[cur][nt] = *(const short8*)(wb_w + nt * 4096 + (kk + 2) * 32);
            }
        }

        // per-wave slab transpose (2 tiles per pass) -> activations -> c,h update
        float* sw = &slab[wave][0];
        #pragma unroll
        for (int t2 = 0; t2 < 2; ++t2) {
            *(f32x4*)(sw + l15 * 20 + kg * 4)        = acc[2 * t2];
            *(f32x4*)(sw + (16 + l15) * 20 + kg * 4) = acc[2 * t2 + 1];
            #pragma unroll
            for (int p = 0; p < 2; ++p) {
                const int b_row = b_lo + p * 8;
                const int bglob = bq * 16 + b_row;
                const int j_g = wave * 16 + t2 * 8 + j_local;
                const float gI = sw[(j_local * 4 + 0) * 20 + b_row];
                const float gF = sw[(j_local * 4 + 1) * 20 + b_row];
                const float gG = sw[(j_local * 4 + 2) * 20 + b_row];
                const float gO = sw[(j_local * 4 + 3) * 20 + b_row];
                const float4 gx = gxr[t2 * 2 + p];
                const float vi = sigmoidf_(gI + gx.x);
                const float vf = sigmoidf_(gF + gx.y);
                const float vg = tanh_fast(gG + gx.z);
                const float vo = sigmoidf_(gO + gx.w);
                const int ci = t2 * 2 + p;
                const float cc = vf * c[ci] + vi * vg;
                c[ci] = cc;
                const float hh = vo * tanh_fast(cc);
                hn[b_row * 264 + j_g] = f2bf(hh);
                hsb[((size_t)bglob * NT + t) * HD + j_g] = hh;
            }
        }
        __syncthreads();
    }
}

// ---------------- output projection + sigmoid ----
__global__ __launch_bounds__(64) void k_out(
    const float* __restrict__ hs, const float* __restrict__ w, const float* __restrict__ bias,
    float* __restrict__ out)
{
    __shared__ float hsh[2 * HD];
    const int bt = blockIdx.x;
    const int tid = threadIdx.x;
    const float4* rev4 = (const float4*)(hs + (size_t)bt * HD);
    const float4* fwd4 = (const float4*)(hs + ((size_t)NBT + bt) * HD);
    for (int i = tid; i < 2 * HD / 4; i += 64)
        ((float4*)hsh)[i] = (i < HD / 4) ? rev4[i] : fwd4[i - HD / 4];
    __syncthreads();
    if (tid < NOUT) {
        const float4* wr = (const float4*)(w + (size_t)tid * (2 * HD));
        float4 acc{0,0,0,0};
        for (int k = 0; k < 2 * HD / 4; ++k) fma4(acc, wr[k], ((const float4*)hsh)[k]);
        out[(size_t)bt * NOUT + tid] = sigmoidf_(hsum4(acc) + bias[tid]);
    }
}

extern "C" void kernel_launch(void* const* d_in, const int* in_sizes, int n_in,
                              void* d_out, int out_size, void* d_ws, size_t ws_size,
                              hipStream_t stream)
{
    const int*   tok   = (const int*)d_in[0];
    const float* emb   = (const float*)d_in[1];
    const float* w3    = (const float*)d_in[2];
    const float* b3    = (const float*)d_in[3];
    const float* w4    = (const float*)d_in[4];
    const float* b4    = (const float*)d_in[5];
    const float* w5    = (const float*)d_in[6];
    const float* b5    = (const float*)d_in[7];
    const float* wih   = (const float*)d_in[8];
    const float* whh   = (const float*)d_in[9];
    const float* bih   = (const float*)d_in[10];
    const float* bhh   = (const float*)d_in[11];
    const float* wih_r = (const float*)d_in[12];
    const float* whh_r = (const float*)d_in[13];
    const float* bih_r = (const float*)d_in[14];
    const float* bhh_r = (const float*)d_in[15];
    const float* h2o_w = (const float*)d_in[16];
    const float* h2o_b = (const float*)d_in[17];

    float* ws  = (float*)d_ws;
    float* rin = ws;                                  // 480,000 f (dead after k_gin)
    float* gin = rin + (size_t)NBT * 3 * NFILT;       // 3,276,800 f  [dir][t][b][1024]
    float* hs  = gin + (size_t)2 * NBT * 1024;        // 819,200 f
    unsigned short* wb  = (unsigned short*)gin;       // conv bf16 W overlays gin
    unsigned short* wb2 = (unsigned short*)rin;       // LSTM bf16 W overlays rin

    k_prep <<<1596, 256, 0, stream>>>(w3, w4, w5, wb);
    k_conv <<<NBT / 2, 512, 0, stream>>>(tok, emb, wb, b3, b4, b5, rin);
    k_gin  <<<NBT / 8, 256, 0, stream>>>(rin, wih, bih, bhh, wih_r, bih_r, bhh_r, gin);
    k_prep2<<<2048, 256, 0, stream>>>(whh, whh_r, wb2);
    k_lstm <<<8, 1024, 0, stream>>>(gin, wb2, hs);
    k_out  <<<NBT, 64, 0, stream>>>(hs, h2o_w, h2o_b, (float*)d_out);
}

// Round 8
// 477.992 us; speedup vs baseline: 1.1582x; 1.0754x over previous
//
#include <hip/hip_runtime.h>
#include <hip/hip_bf16.h>

#define NB 64
#define NT 25
#define NS 50
#define EMBD 300
#define NFILT 100
#define HD 256
#define NOUT 31
#define NBT (NB*NT)

#define KP3 928
#define KP4 1216
#define KP5 1504
#define XS_LEN 15104   // 50*300 = 15000 + pad (max read 45*300+1504 = 15004)

typedef __attribute__((ext_vector_type(8))) short short8;
typedef __attribute__((ext_vector_type(4))) float f32x4;

__device__ __forceinline__ float hsum4(float4 a) { return (a.x + a.y) + (a.z + a.w); }
__device__ __forceinline__ void fma4(float4& a, float4 w, float4 x) {
    a.x = fmaf(w.x, x.x, a.x); a.y = fmaf(w.y, x.y, a.y);
    a.z = fmaf(w.z, x.z, a.z); a.w = fmaf(w.w, x.w, a.w);
}
__device__ __forceinline__ float sigmoidf_(float x) { return 1.0f / (1.0f + __expf(-x)); }
__device__ __forceinline__ float tanh_fast(float x) {
    x = fminf(fmaxf(x, -15.0f), 15.0f);
    const float e = __expf(2.0f * x);
    return (e - 1.0f) / (e + 1.0f);
}

__device__ __forceinline__ unsigned short f2bf(float f) {
    union { float f; unsigned u; } v; v.f = f;
    unsigned r = v.u + 0x7FFF + ((v.u >> 16) & 1);   // RNE
    return (unsigned short)(r >> 16);
}

// 8 bf16 from an 8-byte-aligned LDS address
__device__ __forceinline__ short8 ld8_a8(const unsigned short* p) {
    short8 r;
    ((uint2*)&r)[0] = *(const uint2*)p;
    ((uint2*)&r)[1] = *(const uint2*)(p + 4);
    return r;
}

// async global->LDS, 16B per lane; dest = uniform base + lane*16
__device__ __forceinline__ void gload_lds16(const unsigned short* g, unsigned short* l) {
    __builtin_amdgcn_global_load_lds(
        (const __attribute__((address_space(1))) unsigned int*)g,
        (__attribute__((address_space(3))) unsigned int*)l, 16, 0, 0);
}

// ---------------- conv weight prep: f32 -> bf16, K padded to 32-mult, F padded to 112
__global__ __launch_bounds__(256) void k_prep(
    const float* __restrict__ w3, const float* __restrict__ w4, const float* __restrict__ w5,
    unsigned short* __restrict__ wb)
{
    const int S0 = 112 * KP3, S1 = S0 + 112 * KP4, S2 = S1 + 112 * KP5;
    int idx = blockIdx.x * 256 + threadIdx.x;
    if (idx >= S2) return;
    int rel, Kp, K; const float* src;
    if (idx < S0)      { rel = idx;      Kp = KP3; K = 900;  src = w3; }
    else if (idx < S1) { rel = idx - S0; Kp = KP4; K = 1200; src = w4; }
    else               { rel = idx - S1; Kp = KP5; K = 1500; src = w5; }
    int f = rel / Kp, k = rel - f * Kp;
    float v = (f < NFILT && k < K) ? src[(size_t)f * K + k] : 0.0f;
    wb[idx] = f2bf(v);
}

// ---------------- LSTM weight prep: tile-major, swizzle baked in ----
// wb2[dir][w=8][kk=8] slices of 4096 ush; within slice element (r,kg,e):
//   off = r*32 + ((kg ^ ((r>>1)&3))*8) + e ; holds W[n=w*128+r][k=kk*32+kg*8+e]
__global__ __launch_bounds__(256) void k_prep2(
    const float* __restrict__ whh, const float* __restrict__ whh_r,
    unsigned short* __restrict__ wb2)
{
    const int idx = blockIdx.x * 256 + threadIdx.x;      // grid = 2048*256 = 524288 exact
    const int dir = idx >> 18;
    const int rem = idx & 262143;
    const int n = rem >> 8, k = rem & 255;
    const int j = n >> 2, gate = n & 3;                  // n' = j*4+gate ordering
    const float* src = dir ? whh_r : whh;
    const float v = src[(size_t)(gate * 256 + j) * 256 + k];
    const int w = n >> 7, r = n & 127;
    const int kk = k >> 5, kg = (k >> 3) & 3, e = k & 7;
    const size_t dst = ((size_t)(dir * 8 + w) * 8 + kk) * 4096
                     + r * 32 + ((kg ^ ((r >> 1) & 3)) * 8) + e;
    wb2[dst] = f2bf(v);
}

// ---------------- conv: 2 samples per WG, 512 threads; MFMA + depth-2 W prefetch ----
__global__ __launch_bounds__(512) void k_conv(
    const int* __restrict__ tok, const float* __restrict__ emb,
    const unsigned short* __restrict__ wb,
    const float* __restrict__ b3, const float* __restrict__ b4, const float* __restrict__ b5,
    float* __restrict__ rin)
{
    __shared__ unsigned short xs[2][XS_LEN];   // ~118 KB
    const int bt0 = blockIdx.x * 2;
    const int tid = threadIdx.x;
    for (int i4 = tid; i4 < 2 * NS * 75; i4 += 512) {
        const int smp = i4 / (NS * 75);
        const int rem = i4 - smp * (NS * 75);
        const int s = rem / 75, e4 = rem - s * 75;
        const int t = tok[(bt0 + smp) * NS + s];
        float4 v = ((const float4*)(emb + (size_t)t * EMBD))[e4];
        uint2 pk;
        pk.x = (unsigned)f2bf(v.x) | ((unsigned)f2bf(v.y) << 16);
        pk.y = (unsigned)f2bf(v.z) | ((unsigned)f2bf(v.w) << 16);
        *(uint2*)(&xs[smp][s * 300 + e4 * 4]) = pk;
    }
    for (int i = NS * EMBD + tid; i < XS_LEN; i += 512) { xs[0][i] = 0; xs[1][i] = 0; }
    __syncthreads();

    const int wave = tid >> 6, lane = tid & 63;
    const int col = lane & 15, kg = lane >> 4;

    for (int job = wave; job < 21; job += 8) {
        const int fsi = job / 7, ntile = job - fsi * 7;
        int Kp, P, obase; const unsigned short* W; const float* bias;
        if (fsi == 0)      { Kp = KP3; P = 48; W = wb;                       bias = b3; obase = 0; }
        else if (fsi == 1) { Kp = KP4; P = 47; W = wb + 112 * KP3;           bias = b4; obase = NFILT; }
        else               { Kp = KP5; P = 46; W = wb + 112 * (KP3 + KP4);   bias = b5; obase = 2 * NFILT; }

        const unsigned short* wrow = W + (size_t)(ntile * 16 + col) * Kp + kg * 8;
        const unsigned short* xb0 = &xs[0][col * 300 + kg * 8];
        const unsigned short* xb1 = &xs[1][col * 300 + kg * 8];
        f32x4 a00 = {0,0,0,0}, a01 = {0,0,0,0}, a02 = {0,0,0,0};
        f32x4 a10 = {0,0,0,0}, a11 = {0,0,0,0}, a12 = {0,0,0,0};

        const int nks = Kp / 32;
        short8 wr0 = *(const short8*)(wrow);
        short8 wr1 = *(const short8*)(wrow + 32);
        for (int ks = 0; ks < nks; ++ks) {
            const int k0 = ks * 32;
            short8 bfrag = wr0;
            wr0 = wr1;
            if (ks + 2 < nks) wr1 = *(const short8*)(wrow + k0 + 64);
            short8 p0 = ld8_a8(xb0 + k0);
            short8 p1 = ld8_a8(xb0 + 16 * 300 + k0);
            short8 p2 = ld8_a8(xb0 + 32 * 300 + k0);
            short8 q0 = ld8_a8(xb1 + k0);
            short8 q1 = ld8_a8(xb1 + 16 * 300 + k0);
            short8 q2 = ld8_a8(xb1 + 32 * 300 + k0);
            a00 = __builtin_amdgcn_mfma_f32_16x16x32_bf16(p0, bfrag, a00, 0, 0, 0);
            a01 = __builtin_amdgcn_mfma_f32_16x16x32_bf16(p1, bfrag, a01, 0, 0, 0);
            a02 = __builtin_amdgcn_mfma_f32_16x16x32_bf16(p2, bfrag, a02, 0, 0, 0);
            a10 = __builtin_amdgcn_mfma_f32_16x16x32_bf16(q0, bfrag, a10, 0, 0, 0);
            a11 = __builtin_amdgcn_mfma_f32_16x16x32_bf16(q1, bfrag, a11, 0, 0, 0);
            a12 = __builtin_amdgcn_mfma_f32_16x16x32_bf16(q2, bfrag, a12, 0, 0, 0);
        }

        float pm0 = -1e30f, pm1 = -1e30f;
        #pragma unroll
        for (int reg = 0; reg < 4; ++reg) {
            pm0 = fmaxf(pm0, a00[reg]); pm0 = fmaxf(pm0, a01[reg]);
            pm1 = fmaxf(pm1, a10[reg]); pm1 = fmaxf(pm1, a11[reg]);
            const int r2 = 32 + kg * 4 + reg;
            if (r2 < P) { pm0 = fmaxf(pm0, a02[reg]); pm1 = fmaxf(pm1, a12[reg]); }
        }
        pm0 = fmaxf(pm0, __shfl_xor(pm0, 16, 64));
        pm0 = fmaxf(pm0, __shfl_xor(pm0, 32, 64));
        pm1 = fmaxf(pm1, __shfl_xor(pm1, 16, 64));
        pm1 = fmaxf(pm1, __shfl_xor(pm1, 32, 64));
        if (lane < 16) {
            const int f = ntile * 16 + lane;
            if (f < NFILT) {
                const float bb = bias[f];
                rin[(size_t)bt0 * (3 * NFILT) + obase + f]       = fmaxf(0.0f, pm0 + bb);
                rin[(size_t)(bt0 + 1) * (3 * NFILT) + obase + f] = fmaxf(0.0f, pm1 + bb);
            }
        }
    }
}

// ---------------- input-gate GEMM; writes gin[dir][t][b][n'], n' = j*4+gate ----
__global__ __launch_bounds__(256) void k_gin(
    const float* __restrict__ rin,
    const float* __restrict__ wih,   const float* __restrict__ bih,   const float* __restrict__ bhh,
    const float* __restrict__ wih_r, const float* __restrict__ bih_r, const float* __restrict__ bhh_r,
    float* __restrict__ gin)
{
    __shared__ float xsh[8 * EMBD];
    const int bt0 = blockIdx.x * 8;
    const int tid = threadIdx.x;
    const float4* src = (const float4*)(rin + (size_t)bt0 * EMBD);
    for (int i4 = tid; i4 < 8 * EMBD / 4; i4 += 256) ((float4*)xsh)[i4] = src[i4];
    __syncthreads();
    for (int g2 = tid; g2 < 2 * 1024; g2 += 256) {
        const int d = g2 >> 10;
        const int g = g2 & 1023;
        const float* wp = (d ? wih_r : wih) + (size_t)g * EMBD;
        const float bb = d ? (bih_r[g] + bhh_r[g]) : (bih[g] + bhh[g]);
        const float4* w4p = (const float4*)wp;
        float4 acc[8];
        #pragma unroll
        for (int r = 0; r < 8; ++r) acc[r] = {0,0,0,0};
        for (int k = 0; k < EMBD / 4; ++k) {
            const float4 wv = w4p[k];
            #pragma unroll
            for (int r = 0; r < 8; ++r) fma4(acc[r], wv, ((const float4*)(xsh + r * EMBD))[k]);
        }
        const int gp = ((g & 255) << 2) | (g >> 8);   // j*4 + gate
        #pragma unroll
        for (int r = 0; r < 8; ++r) {
            const int bt = bt0 + r;
            const int b = bt / NT, t = bt - b * NT;
            gin[(((size_t)d * NT + t) * NB + b) * 1024 + gp] = hsum4(acc[r]) + bb;
        }
    }
}

// ---------------- recurrence: 8 WGs x 512 thr; W streamed via global_load_lds DMA ----
// Wave w owns n-cols [w*128, w*128+128). Per-wave 2-slot LDS ring, counted vmcnt.
__global__ __launch_bounds__(512, 1) void k_lstm(
    const float* __restrict__ gin,          // [dir][t][64][1024] f32, n' = j*4+gate
    const unsigned short* __restrict__ wb2, // tile-major swizzled (see k_prep2)
    float* __restrict__ hs)                 // [dir][b*NT+t][256] f32
{
    const int bid = blockIdx.x;
    const int dir = bid >> 2, bq = bid & 3;
    const int tid = threadIdx.x;
    const int wave = tid >> 6, lane = tid & 63;
    const int l15 = lane & 15, kg = lane >> 4;
    const int m = l15 & 3, quad = l15 >> 2;

    __shared__ __align__(16) unsigned short wring[8][2][4096];  // 128 KB
    __shared__ __align__(16) unsigned short hb[2][16 * 264];    // 16.5 KB

    for (int i = tid; i < 16 * 264; i += 512) hb[0][i] = 0;
    __syncthreads();

    const unsigned short* wsrc = wb2 + ((size_t)(dir * 8 + wave) * 8) * 4096;  // + kk*4096
    unsigned short* wd0 = &wring[wave][0][0];
    unsigned short* wd1 = &wring[wave][1][0];

    const float* gb = gin + (size_t)dir * (NT * NB * 1024);
    float* hsb = hs + (size_t)dir * NBT * HD;

    const int b_row = kg * 4 + m;          // batch within quarter [0,16)
    const int bglob = bq * 16 + b_row;

    float c[8] = {0.f,0.f,0.f,0.f,0.f,0.f,0.f,0.f};

    for (int s = 0; s < NT; ++s) {
        const int t = dir ? s : (NT - 1 - s);
        const unsigned short* hc = hb[s & 1];
        unsigned short* hn = hb[(s + 1) & 1];

        // issue gin loads (8x float4) — pinned before the W stream by asm fences below
        float4 gxr[8];
        #pragma unroll
        for (int nt = 0; nt < 8; ++nt) {
            const int j_g = wave * 32 + nt * 4 + quad;
            gxr[nt] = *(const float4*)(gb + (((size_t)t * NB + bglob) << 10) + j_g * 4);
        }
        // issue W tiles 0,1 via DMA (8 instrs each; no VGPRs consumed)
        #pragma unroll
        for (int i = 0; i < 8; ++i) gload_lds16(wsrc + i * 512 + lane * 8, wd0 + i * 512);
        #pragma unroll
        for (int i = 0; i < 8; ++i) gload_lds16(wsrc + 4096 + i * 512 + lane * 8, wd1 + i * 512);

        f32x4 acc[8];
        #pragma unroll
        for (int nt = 0; nt < 8; ++nt) acc[nt] = (f32x4){0.f, 0.f, 0.f, 0.f};

        #pragma unroll
        for (int kk = 0; kk < 8; ++kk) {
            if (kk < 7) asm volatile("s_waitcnt vmcnt(8)" ::: "memory");
            else        asm volatile("s_waitcnt vmcnt(0)" ::: "memory");
            __builtin_amdgcn_sched_barrier(0);
            const unsigned short* wt = (kk & 1) ? wd1 : wd0;
            const short8 av = *(const short8*)(hc + l15 * 264 + kk * 32 + kg * 8);
            #pragma unroll
            for (int nt = 0; nt < 8; ++nt) {
                const int row = nt * 16 + l15;
                const short8 bbf = *(const short8*)(wt + row * 32 + ((kg ^ ((row >> 1) & 3)) * 8));
                acc[nt] = __builtin_amdgcn_mfma_f32_16x16x32_bf16(av, bbf, acc[nt], 0, 0, 0);
            }
            if (kk + 2 < 8) {
                asm volatile("s_waitcnt lgkmcnt(0)" ::: "memory");  // ds_reads of this slot done
                unsigned short* wref = (kk & 1) ? wd1 : wd0;
                #pragma unroll
                for (int i = 0; i < 8; ++i)
                    gload_lds16(wsrc + (kk + 2) * 4096 + i * 512 + lane * 8, wref + i * 512);
            }
        }

        // phase 3: in-register 4x4 quad transpose -> activations -> c,h update
        #pragma unroll
        for (int nt = 0; nt < 8; ++nt) {
            float r0 = acc[nt][0], r1 = acc[nt][1], r2 = acc[nt][2], r3 = acc[nt][3];
            { float x = (m & 1) ? r0 : r1; x = __shfl_xor(x, 1, 64); if (m & 1) r0 = x; else r1 = x; }
            { float x = (m & 1) ? r2 : r3; x = __shfl_xor(x, 1, 64); if (m & 1) r2 = x; else r3 = x; }
            { float x = (m & 2) ? r0 : r2; x = __shfl_xor(x, 2, 64); if (m & 2) r0 = x; else r2 = x; }
            { float x = (m & 2) ? r1 : r3; x = __shfl_xor(x, 2, 64); if (m & 2) r1 = x; else r3 = x; }
            const float4 gx = gxr[nt];
            const float vi = sigmoidf_(r0 + gx.x);
            const float vf = sigmoidf_(r1 + gx.y);
            const float vg = tanh_fast(r2 + gx.z);
            const float vo = sigmoidf_(r3 + gx.w);
            const float cc = vf * c[nt] + vi * vg;
            c[nt] = cc;
            const float hh = vo * tanh_fast(cc);
            const int j_g = wave * 32 + nt * 4 + quad;
            hn[b_row * 264 + j_g] = f2bf(hh);
            hsb[((size_t)bglob * NT + t) * HD + j_g] = hh;
        }
        __syncthreads();   // drains vmcnt/lgkm -> clean counts next step
    }
}

// ---------------- output projection + sigmoid ----
__global__ __launch_bounds__(64) void k_out(
    const float* __restrict__ hs, const float* __restrict__ w, const float* __restrict__ bias,
    float* __restrict__ out)
{
    __shared__ float hsh[2 * HD];
    const int bt = blockIdx.x;
    const int tid = threadIdx.x;
    const float4* rev4 = (const float4*)(hs + (size_t)bt * HD);
    const float4* fwd4 = (const float4*)(hs + ((size_t)NBT + bt) * HD);
    for (int i = tid; i < 2 * HD / 4; i += 64)
        ((float4*)hsh)[i] = (i < HD / 4) ? rev4[i] : fwd4[i - HD / 4];
    __syncthreads();
    if (tid < NOUT) {
        const float4* wr = (const float4*)(w + (size_t)tid * (2 * HD));
        float4 acc{0,0,0,0};
        for (int k = 0; k < 2 * HD / 4; ++k) fma4(acc, wr[k], ((const float4*)hsh)[k]);
        out[(size_t)bt * NOUT + tid] = sigmoidf_(hsum4(acc) + bias[tid]);
    }
}

extern "C" void kernel_launch(void* const* d_in, const int* in_sizes, int n_in,
                              void* d_out, int out_size, void* d_ws, size_t ws_size,
                              hipStream_t stream)
{
    const int*   tok   = (const int*)d_in[0];
    const float* emb   = (const float*)d_in[1];
    const float* w3    = (const float*)d_in[2];
    const float* b3    = (const float*)d_in[3];
    const float* w4    = (const float*)d_in[4];
    const float* b4    = (const float*)d_in[5];
    const float* w5    = (const float*)d_in[6];
    const float* b5    = (const float*)d_in[7];
    const float* wih   = (const float*)d_in[8];
    const float* whh   = (const float*)d_in[9];
    const float* bih   = (const float*)d_in[10];
    const float* bhh   = (const float*)d_in[11];
    const float* wih_r = (const float*)d_in[12];
    const float* whh_r = (const float*)d_in[13];
    const float* bih_r = (const float*)d_in[14];
    const float* bhh_r = (const float*)d_in[15];
    const float* h2o_w = (const float*)d_in[16];
    const float* h2o_b = (const float*)d_in[17];

    float* ws  = (float*)d_ws;
    float* rin = ws;                                  // 480,000 f (dead after k_gin)
    float* gin = rin + (size_t)NBT * 3 * NFILT;       // 3,276,800 f  [dir][t][b][1024]
    float* hs  = gin + (size_t)2 * NBT * 1024;        // 819,200 f
    unsigned short* wb  = (unsigned short*)gin;       // conv bf16 W overlays gin
    unsigned short* wb2 = (unsigned short*)rin;       // LSTM bf16 W overlays rin

    k_prep <<<1596, 256, 0, stream>>>(w3, w4, w5, wb);
    k_conv <<<NBT / 2, 512, 0, stream>>>(tok, emb, wb, b3, b4, b5, rin);
    k_gin  <<<NBT / 8, 256, 0, stream>>>(rin, wih, bih, bhh, wih_r, bih_r, bhh_r, gin);
    k_prep2<<<2048, 256, 0, stream>>>(whh, whh_r, wb2);
    k_lstm <<<8, 512, 0, stream>>>(gin, wb2, hs);
    k_out  <<<NBT, 64, 0, stream>>>(hs, h2o_w, h2o_b, (float*)d_out);
}